// Round 7
// baseline (192.870 us; speedup 1.0000x reference)
//
#include <hip/hip_runtime.h>

// Classwise circular-buffer queue update.
// occ_i = rank of proposal i within its class (original index order).
// slot  = (tail[l] + occ) % Q.  Proposal i is the FINAL writer of its slot
// iff occ >= k_l - Q (last min(k,Q) ranks cover distinct slots exactly once).
// => conflict-free scatter of proposal index into idx[C*Q], then one
// streaming gather pass building the output.

typedef float vf4 __attribute__((ext_vector_type(4)));
typedef int   vi4 __attribute__((ext_vector_type(4)));

#define HBLK 1024  // proposals per histogram block
#define RPW  4     // rows per wave in the gather (MLP depth)

// Zero own cnt row, then histogram this block's labels into it.
__global__ void k_hist(const int* __restrict__ lab, int* __restrict__ cnt,
                       int N, int C) {
    int b = blockIdx.x;
    int t = threadIdx.x;
    int* row = cnt + (size_t)b * C;
    for (int j = t; j < C; j += HBLK) row[j] = 0;
    __syncthreads();
    int i = b * HBLK + t;
    if (i < N) {
        int l = lab[i];
        if (l >= 0 && l < C) atomicAdd(&row[l], 1);
    }
}

// Column-wise exclusive prefix over blocks; total per label; init idx = -1.
__global__ void k_prefix(int* __restrict__ cnt, int* __restrict__ ktot,
                         int* __restrict__ idx, int C, int NB, int Q) {
    int l = blockIdx.x * blockDim.x + threadIdx.x;
    if (l >= C) return;
    int run = 0;
    for (int b = 0; b < NB; ++b) {
        int t = cnt[(size_t)b * C + l];
        cnt[(size_t)b * C + l] = run;  // exclusive prefix per (block,label)
        run += t;
    }
    ktot[l] = run;                     // total count per label
    for (int q = 0; q < Q; ++q) idx[l * Q + q] = -1;
}

__global__ void k_slots(const int* __restrict__ lab, const int* __restrict__ tail,
                        const int* __restrict__ cnt, const int* __restrict__ ktot,
                        int* __restrict__ idx, int N, int C, int Q) {
    __shared__ __align__(16) int slab[HBLK];
    int b = blockIdx.x;
    int t = threadIdx.x;
    int i = b * HBLK + t;
    int l = (i < N) ? lab[i] : -1;
    slab[t] = l;
    __syncthreads();
    if (l < 0 || l >= C) return;
    // local rank within block: count slab[j]==l for j<t, 4 labels/iter
    const vi4* slab4 = (const vi4*)slab;
    int local = 0;
    int nw = t >> 2;
    for (int w = 0; w < nw; ++w) {
        vi4 v = slab4[w];  // broadcast ds_read_b128
        local += (v.x == l) + (v.y == l) + (v.z == l) + (v.w == l);
    }
    for (int j = t & ~3; j < t; ++j) local += (slab[j] == l);
    int occ = cnt[(size_t)b * C + l] + local;
    int kk = ktot[l];
    if (occ >= kk - Q) {
        int s = (tail[l] + occ) % Q;
        if (s < 0) s += Q;            // python-style mod (positive divisor)
        idx[l * Q + s] = i;           // unique (class,slot) per qualifier
    }
}

// Gather (F==256): 256-thread block = 4 waves; each wave copies RPW whole
// consecutive rows (64 lanes x float4 = 1KB/row).  Per thread: RPW idx
// loads issued together, then RPW independent 16B loads, then RPW NT
// stores -> 4x memory-level parallelism vs one-row-per-wave.
__global__ void k_gather_d(const vf4* __restrict__ feat,
                           const vf4* __restrict__ queue,
                           const int* __restrict__ idx,
                           vf4* __restrict__ out, int R) {
    int wave = threadIdx.x >> 6;
    int lane = threadIdx.x & 63;
    int r0 = (blockIdx.x * 4 + wave) * RPW;
    if (r0 + RPW <= R) {
        int id[RPW];
        #pragma unroll
        for (int k = 0; k < RPW; ++k) id[k] = idx[r0 + k];
        const vf4* src[RPW];
        #pragma unroll
        for (int k = 0; k < RPW; ++k)
            src[k] = (id[k] >= 0) ? (feat  + ((size_t)id[k] << 6) + lane)
                                  : (queue + ((size_t)(r0 + k) << 6) + lane);
        vf4 v[RPW];
        #pragma unroll
        for (int k = 0; k < RPW; ++k) v[k] = *src[k];
        #pragma unroll
        for (int k = 0; k < RPW; ++k)
            __builtin_nontemporal_store(v[k], out + ((size_t)(r0 + k) << 6) + lane);
    } else {
        for (int r = r0; r < R; ++r) {
            int id = idx[r];
            const vf4* s = (id >= 0) ? (feat  + ((size_t)id << 6) + lane)
                                     : (queue + ((size_t)r << 6) + lane);
            __builtin_nontemporal_store(*s, out + ((size_t)r << 6) + lane);
        }
    }
}

// Generic fallback (any F divisible by 4).
__global__ void k_gather_g(const vf4* __restrict__ feat,
                           const vf4* __restrict__ queue,
                           const int* __restrict__ idx,
                           vf4* __restrict__ out,
                           long long total4, int F4) {
    long long stride = (long long)gridDim.x * blockDim.x;
    for (long long g = (long long)blockIdx.x * blockDim.x + threadIdx.x;
         g < total4; g += stride) {
        int r = (int)(g / F4);
        int c = (int)(g - (long long)r * F4);
        int id = idx[r];
        const vf4* src = (id >= 0) ? (feat + (size_t)id * F4 + c)
                                   : (queue + (size_t)r * F4 + c);
        __builtin_nontemporal_store(*src, &out[g]);
    }
}

extern "C" void kernel_launch(void* const* d_in, const int* in_sizes, int n_in,
                              void* d_out, int out_size, void* d_ws, size_t ws_size,
                              hipStream_t stream) {
    const float* feat  = (const float*)d_in[0];
    const float* queue = (const float*)d_in[1];
    const int*   lab   = (const int*)d_in[2];
    const int*   tail  = (const int*)d_in[3];

    const int N = in_sizes[2];
    const int C = in_sizes[3];
    const int F = in_sizes[0] / N;
    const int Q = in_sizes[1] / (C * F);
    const int NB = (N + HBLK - 1) / HBLK;

    int* idx  = (int*)d_ws;                    // C*Q
    int* cnt  = idx + (size_t)C * Q;           // NB*C
    int* ktot = cnt + (size_t)NB * C;          // C

    k_hist<<<NB, HBLK, 0, stream>>>(lab, cnt, N, C);
    k_prefix<<<(C + 255) / 256, 256, 0, stream>>>(cnt, ktot, idx, C, NB, Q);
    k_slots<<<NB, HBLK, 0, stream>>>(lab, tail, cnt, ktot, idx, N, C, Q);

    const long long R = (long long)C * Q;
    const int F4 = F / 4;
    const long long total4 = R * F4;
    if (F == 256) {
        const int rows_per_block = 4 * RPW;          // 4 waves x RPW rows
        const int blocks = (int)((R + rows_per_block - 1) / rows_per_block);
        k_gather_d<<<blocks, 256, 0, stream>>>((const vf4*)feat,
                                               (const vf4*)queue, idx,
                                               (vf4*)d_out, (int)R);
    } else {
        int gblocks = 2048;
        long long need = (total4 + 255) / 256;
        if (need < gblocks) gblocks = (int)need;
        k_gather_g<<<gblocks, 256, 0, stream>>>((const vf4*)feat,
                                                (const vf4*)queue, idx,
                                                (vf4*)d_out, total4, F4);
    }
}

// Round 8
// 182.251 us; speedup vs baseline: 1.0583x; 1.0583x over previous
//
#include <hip/hip_runtime.h>

// Classwise circular-buffer queue update.
// occ_i = rank of proposal i within its class (original index order).
// slot  = (tail[l] + occ) % Q.  Proposal i is the FINAL writer of its slot
// iff occ >= k_l - Q (last min(k,Q) ranks cover distinct slots exactly once).
// => conflict-free scatter of proposal index into idx[C*Q], then one
// streaming gather pass building the output.

typedef float vf4 __attribute__((ext_vector_type(4)));
typedef int   vi4 __attribute__((ext_vector_type(4)));

#define HBLK 1024  // proposals per histogram chunk (cnt row granularity)

// Full-occupancy workspace init: idx = -1, cnt = 0.  Vectorized grid-stride.
__global__ void k_zero(int* __restrict__ idx, long long nIdx,
                       int* __restrict__ cnt, long long nCnt) {
    long long stride = (long long)gridDim.x * blockDim.x;
    long long g0 = (long long)blockIdx.x * blockDim.x + threadIdx.x;
    vi4* idx4 = (vi4*)idx;
    vi4* cnt4 = (vi4*)cnt;
    vi4 mone; mone.x = mone.y = mone.z = mone.w = -1;
    vi4 zero; zero.x = zero.y = zero.z = zero.w = 0;
    long long n4i = nIdx >> 2, n4c = nCnt >> 2;
    for (long long g = g0; g < n4i; g += stride) idx4[g] = mone;
    for (long long g = g0; g < n4c; g += stride) cnt4[g] = zero;
    // tails (if sizes not divisible by 4)
    if (g0 < (nIdx & 3)) idx[n4i * 4 + g0] = -1;
    if (g0 < (nCnt & 3)) cnt[n4c * 4 + g0] = 0;
}

// Pure-atomic chunk histogram: cnt[(i/HBLK)*C + l]++.  High occupancy.
__global__ void k_hist(const int* __restrict__ lab, int* __restrict__ cnt,
                       int N, int C) {
    int i = blockIdx.x * blockDim.x + threadIdx.x;
    if (i < N) {
        int l = lab[i];
        if (l >= 0 && l < C) atomicAdd(&cnt[(size_t)(i >> 10) * C + l], 1);
    }
}

// Column-wise exclusive prefix over chunks; total per label.
__global__ void k_prefix(int* __restrict__ cnt, int* __restrict__ ktot,
                         int C, int NB) {
    int l = blockIdx.x * blockDim.x + threadIdx.x;
    if (l >= C) return;
    int run = 0;
    for (int b = 0; b < NB; ++b) {
        int t = cnt[(size_t)b * C + l];
        cnt[(size_t)b * C + l] = run;  // exclusive prefix per (chunk,label)
        run += t;
    }
    ktot[l] = run;                     // total count per label
}

__global__ void k_slots(const int* __restrict__ lab, const int* __restrict__ tail,
                        const int* __restrict__ cnt, const int* __restrict__ ktot,
                        int* __restrict__ idx, int N, int C, int Q) {
    __shared__ __align__(16) int slab[HBLK];
    int b = blockIdx.x;
    int t = threadIdx.x;
    int i = b * HBLK + t;
    int l = (i < N) ? lab[i] : -1;
    slab[t] = l;
    __syncthreads();
    if (l < 0 || l >= C) return;
    // local rank within chunk: count slab[j]==l for j<t, 4 labels/iter
    const vi4* slab4 = (const vi4*)slab;
    int local = 0;
    int nw = t >> 2;
    for (int w = 0; w < nw; ++w) {
        vi4 v = slab4[w];  // broadcast ds_read_b128
        local += (v.x == l) + (v.y == l) + (v.z == l) + (v.w == l);
    }
    for (int j = t & ~3; j < t; ++j) local += (slab[j] == l);
    int occ = cnt[(size_t)b * C + l] + local;
    int kk = ktot[l];
    if (occ >= kk - Q) {
        int s = (tail[l] + occ) % Q;
        if (s < 0) s += Q;            // python-style mod (positive divisor)
        idx[l * Q + s] = i;           // unique (class,slot) per qualifier
    }
}

// Direct-mapped gather (F==256): one wave per 1KB row, no loop.
// Plain (cached) loads; NT store (output never re-read).  [round-6 champion]
__global__ void k_gather_d(const vf4* __restrict__ feat,
                           const vf4* __restrict__ queue,
                           const int* __restrict__ idx,
                           vf4* __restrict__ out, long long total4) {
    long long g = (long long)blockIdx.x * blockDim.x + threadIdx.x;
    if (g >= total4) return;
    int r = (int)(g >> 6);
    int c = (int)(g & 63);
    int id = idx[r];  // one line per wave, broadcast
    const vf4* src = (id >= 0) ? (feat + ((size_t)id << 6) + c)
                               : (queue + ((size_t)r << 6) + c);
    __builtin_nontemporal_store(*src, &out[g]);
}

// Generic fallback (any F divisible by 4).
__global__ void k_gather_g(const vf4* __restrict__ feat,
                           const vf4* __restrict__ queue,
                           const int* __restrict__ idx,
                           vf4* __restrict__ out,
                           long long total4, int F4) {
    long long stride = (long long)gridDim.x * blockDim.x;
    for (long long g = (long long)blockIdx.x * blockDim.x + threadIdx.x;
         g < total4; g += stride) {
        int r = (int)(g / F4);
        int c = (int)(g - (long long)r * F4);
        int id = idx[r];
        const vf4* src = (id >= 0) ? (feat + (size_t)id * F4 + c)
                                   : (queue + (size_t)r * F4 + c);
        __builtin_nontemporal_store(*src, &out[g]);
    }
}

extern "C" void kernel_launch(void* const* d_in, const int* in_sizes, int n_in,
                              void* d_out, int out_size, void* d_ws, size_t ws_size,
                              hipStream_t stream) {
    const float* feat  = (const float*)d_in[0];
    const float* queue = (const float*)d_in[1];
    const int*   lab   = (const int*)d_in[2];
    const int*   tail  = (const int*)d_in[3];

    const int N = in_sizes[2];
    const int C = in_sizes[3];
    const int F = in_sizes[0] / N;
    const int Q = in_sizes[1] / (C * F);
    const int NB = (N + HBLK - 1) / HBLK;

    int* idx  = (int*)d_ws;                    // C*Q
    int* cnt  = idx + (size_t)C * Q;           // NB*C
    int* ktot = cnt + (size_t)NB * C;          // C

    const long long R = (long long)C * Q;
    k_zero<<<2048, 256, 0, stream>>>(idx, R, cnt, (long long)NB * C);
    k_hist<<<(N + 255) / 256, 256, 0, stream>>>(lab, cnt, N, C);
    k_prefix<<<(C + 255) / 256, 256, 0, stream>>>(cnt, ktot, C, NB);
    k_slots<<<NB, HBLK, 0, stream>>>(lab, tail, cnt, ktot, idx, N, C, Q);

    const int F4 = F / 4;
    const long long total4 = R * F4;
    if (F == 256) {
        const int blocks = (int)((total4 + 511) / 512);
        k_gather_d<<<blocks, 512, 0, stream>>>((const vf4*)feat,
                                               (const vf4*)queue, idx,
                                               (vf4*)d_out, total4);
    } else {
        int gblocks = 2048;
        long long need = (total4 + 255) / 256;
        if (need < gblocks) gblocks = (int)need;
        k_gather_g<<<gblocks, 256, 0, stream>>>((const vf4*)feat,
                                                (const vf4*)queue, idx,
                                                (vf4*)d_out, total4, F4);
    }
}